// Round 1
// baseline (110.827 us; speedup 1.0000x reference)
//
#include <hip/hip_runtime.h>
#include <stdint.h>

typedef unsigned short ushort_t;
typedef __attribute__((ext_vector_type(8))) short short8;
typedef __attribute__((ext_vector_type(4))) float f32x4;
typedef __attribute__((ext_vector_type(4))) unsigned int u32x4;

#define TOK  16384
#define DIM  512
#define NEXP 10

// ---- helpers ----
__device__ __forceinline__ unsigned short f2bf(float f) {  // RNE f32->bf16
  union { float f; uint32_t u; } v; v.f = f;
  uint32_t u = v.u;
  uint32_t r = (u + 0x7fffu + ((u >> 16) & 1u)) >> 16;
  return (unsigned short)r;
}
__device__ __forceinline__ float bflo_to_f(uint32_t u) {  // low half bf16 -> f32
  union { uint32_t u; float f; } v; v.u = u << 16; return v.f;
}
__device__ __forceinline__ float bfhi_to_f(uint32_t u) {  // high half bf16 -> f32
  union { uint32_t u; float f; } v; v.u = u & 0xffff0000u; return v.f;
}

// ---- kernel 1: router -> combined weights c[N][10] ----
__global__ void k_router(const float* __restrict__ sl, const float* __restrict__ shl,
                         float* __restrict__ c) {
  int n = blockIdx.x * 256 + threadIdx.x;
  if (n >= TOK) return;
  float l[8];
  float m = -1e30f;
#pragma unroll
  for (int i = 0; i < 8; ++i) { l[i] = sl[n*8 + i]; m = fmaxf(m, l[i]); }
  float s = 0.f;
#pragma unroll
  for (int i = 0; i < 8; ++i) { l[i] = expf(l[i] - m); s += l[i]; }
  float inv = 1.f / s;
#pragma unroll
  for (int i = 0; i < 8; ++i) l[i] *= inv;
  // top-2 (ties -> lowest index, matching lax.top_k)
  int i1 = 0; float v1 = l[0];
#pragma unroll
  for (int i = 1; i < 8; ++i) if (l[i] > v1) { v1 = l[i]; i1 = i; }
  int i2 = -1; float v2 = -1.f;
#pragma unroll
  for (int i = 0; i < 8; ++i) if (i != i1 && l[i] > v2) { v2 = l[i]; i2 = i; }
  float rs = 1.f / (v1 + v2 + 1e-6f);
  float w1 = v1 * rs, w2 = v2 * rs;
#pragma unroll
  for (int i = 0; i < 8; ++i) {
    float oi = (i == i1) ? w1 : ((i == i2) ? w2 : 0.f);
    c[n*NEXP + i] = oi;
  }
  float s0 = shl[n*2], s1 = shl[n*2 + 1];
  float mm = fmaxf(s0, s1);
  float e0 = expf(s0 - mm), e1 = expf(s1 - mm);
  float si = 1.f / (e0 + e1);
  c[n*NEXP + 8] = e0 * si;
  c[n*NEXP + 9] = e1 * si;
}

// ---- kernel 2: x fp32 -> bf16 ----
__global__ void k_cvtx(const float* __restrict__ x, ushort_t* __restrict__ xb) {
  int i = (blockIdx.x * 256 + threadIdx.x) * 8;
  f32x4 v0 = *(const f32x4*)(x + i);
  f32x4 v1 = *(const f32x4*)(x + i + 4);
  u32x4 o;
  o[0] = (uint32_t)f2bf(v0[0]) | ((uint32_t)f2bf(v0[1]) << 16);
  o[1] = (uint32_t)f2bf(v0[2]) | ((uint32_t)f2bf(v0[3]) << 16);
  o[2] = (uint32_t)f2bf(v1[0]) | ((uint32_t)f2bf(v1[1]) << 16);
  o[3] = (uint32_t)f2bf(v1[2]) | ((uint32_t)f2bf(v1[3]) << 16);
  *(u32x4*)(xb + i) = o;
}

// ---- kernel 3: W[e][d][f] fp32 -> Wt[e][f][d] bf16 (transposed for B staging) ----
__global__ void k_trw(const float* __restrict__ wspec, const float* __restrict__ wsh,
                      ushort_t* __restrict__ wt) {
  __shared__ float t[32][33];
  int e = blockIdx.z;
  const float* src = (e < 8) ? (wspec + e * DIM * DIM) : (wsh + (e - 8) * DIM * DIM);
  int tx = threadIdx.x, ty = threadIdx.y;
  int d = blockIdx.y * 32 + ty, f = blockIdx.x * 32 + tx;
  t[ty][tx] = src[d * DIM + f];
  __syncthreads();
  int fo = blockIdx.x * 32 + ty, dd = blockIdx.y * 32 + tx;
  wt[(size_t)e * DIM * DIM + fo * DIM + dd] = f2bf(t[tx][ty]);
}

// ---- kernel 4: fused MoE GEMM ----
// out[n][f] = sum_e c[n][e] * ( sum_k x[n][k] * W_e[k][f] + b_e[f] )
// 128x128 tile, BK=64, 4 waves (2x2), mfma_f32_16x16x32_bf16.
// A scaled per-expert in registers; one accumulator across all 10 experts.
__global__ __launch_bounds__(256, 2)
void k_moe(const ushort_t* __restrict__ xb, const ushort_t* __restrict__ wt,
           const float* __restrict__ cws, const float* __restrict__ bspec,
           const float* __restrict__ bsh, float* __restrict__ out) {
  // LDS: rows of 64 bf16 = 128 B; physical byte = row*128 + ((2k) ^ ((row&7)<<4))
  __shared__ ushort_t aB[2][128 * 64];   // 2 x 16 KB, x tile (double buf across ks)
  __shared__ ushort_t bB[2][128 * 64];   // 2 x 16 KB, W tile (double buf across experts)
  __shared__ float cT[NEXP * 128];       // c transposed [e][row]
  __shared__ float bT[NEXP * 128];       // bias [e][col]

  const int tid  = threadIdx.x;
  const int lane = tid & 63;
  const int w    = tid >> 6;
  const int wr   = w >> 1, wc = w & 1;
  const int bid  = blockIdx.x;
  const int trow = (bid & 127) << 7;   // consecutive bids share tcol -> B L2-resident per XCD
  const int tcol = (bid >> 7) << 7;

  // stage cT (transposed) and bT via plain ds-writes
  for (int i = tid; i < NEXP * 128; i += 256) {
    int r = i / NEXP, e = i - r * NEXP;
    cT[e * 128 + r] = cws[(trow + r) * NEXP + e];
  }
  for (int i = tid; i < NEXP * 128; i += 256) {
    int e = i >> 7, col = i & 127;
    bT[i] = (e < 8) ? bspec[e * DIM + tcol + col] : bsh[(e - 8) * DIM + tcol + col];
  }

  // global_load_lds staging: lane writes linear LDS (base + lane*16); global source
  // pre-swizzled so that swizzled ds_reads see [row][k] with byte ^= ((row&7)<<4).
  int goff[4];
  const int pb = (w << 12) + (lane << 4);
#pragma unroll
  for (int i = 0; i < 4; ++i) {
    int p   = pb + (i << 10);
    int row = p >> 7;
    int kb  = (p & 127) ^ ((row & 7) << 4);
    goff[i] = row * DIM + (kb >> 1);
  }
  const ushort_t* aSrc     = xb + trow * DIM;
  const ushort_t* bSrcBase = wt + tcol * DIM;

  auto stageA = [&](int ks, int buf) {
    const ushort_t* s = aSrc + (ks << 6);
#pragma unroll
    for (int i = 0; i < 4; ++i)
      __builtin_amdgcn_global_load_lds(
          (const __attribute__((address_space(1))) void*)(s + goff[i]),
          (__attribute__((address_space(3))) void*)((char*)(&aB[buf][0]) + (w << 12) + (i << 10)),
          16, 0, 0);
  };
  auto stageB = [&](int ks, int e, int buf) {
    const ushort_t* s = bSrcBase + (e << 18) + (ks << 6);
#pragma unroll
    for (int i = 0; i < 4; ++i)
      __builtin_amdgcn_global_load_lds(
          (const __attribute__((address_space(1))) void*)(s + goff[i]),
          (__attribute__((address_space(3))) void*)((char*)(&bB[buf][0]) + (w << 12) + (i << 10)),
          16, 0, 0);
  };

  f32x4 acc[4][4];
#pragma unroll
  for (int a = 0; a < 4; ++a)
#pragma unroll
    for (int b = 0; b < 4; ++b) acc[a][b] = (f32x4){0.f, 0.f, 0.f, 0.f};

  stageA(0, 0);
  stageB(0, 0, 0);

  float a32[4][2][8];  // unpacked f32 A fragments, shared across the 10 experts

  for (int ks = 0; ks < 8; ++ks) {
    for (int e = 0; e < NEXP; ++e) {
      __syncthreads();  // drains vmcnt/lgkm: prior stages complete & visible
      // prefetch next tiles (consumed after the NEXT barrier)
      if (e < 9)        stageB(ks, e + 1, (e + 1) & 1);
      else if (ks < 7)  stageB(ks + 1, 0, 0);
      if (e == 8 && ks < 7) stageA(ks + 1, (ks + 1) & 1);

      if (e == 0) {  // load + unpack A[ks] once, reuse for all experts
        const char* ab = (const char*)(&aB[ks & 1][0]);
#pragma unroll
        for (int rb = 0; rb < 4; ++rb) {
          int row = wr * 64 + rb * 16 + (lane & 15);
#pragma unroll
          for (int ksl = 0; ksl < 2; ++ksl) {
            int kb = ((ksl << 6) + ((lane >> 4) << 4)) ^ ((row & 7) << 4);
            u32x4 v = *(const u32x4*)(ab + row * 128 + kb);
#pragma unroll
            for (int j = 0; j < 4; ++j) {
              a32[rb][ksl][2 * j]     = bflo_to_f(v[j]);
              a32[rb][ksl][2 * j + 1] = bfhi_to_f(v[j]);
            }
          }
        }
      }

      float ce[4];
#pragma unroll
      for (int rb = 0; rb < 4; ++rb)
        ce[rb] = cT[(e << 7) + wr * 64 + rb * 16 + (lane & 15)];

      const char* bb = (const char*)(&bB[e & 1][0]);
      u32x4 bf4[2][4];
#pragma unroll
      for (int ksl = 0; ksl < 2; ++ksl)
#pragma unroll
        for (int cb = 0; cb < 4; ++cb) {
          int col = wc * 64 + cb * 16 + (lane & 15);
          int kb  = ((ksl << 6) + ((lane >> 4) << 4)) ^ ((col & 7) << 4);
          bf4[ksl][cb] = *(const u32x4*)(bb + col * 128 + kb);
        }

#pragma unroll
      for (int ksl = 0; ksl < 2; ++ksl) {
#pragma unroll
        for (int rb = 0; rb < 4; ++rb) {
          u32x4 q;
#pragma unroll
          for (int j = 0; j < 4; ++j) {
            float lo = a32[rb][ksl][2 * j]     * ce[rb];
            float hi = a32[rb][ksl][2 * j + 1] * ce[rb];
            uint32_t r;
            asm("v_cvt_pk_bf16_f32 %0, %1, %2" : "=v"(r) : "v"(lo), "v"(hi));
            q[j] = r;
          }
          short8 a8 = __builtin_bit_cast(short8, q);
#pragma unroll
          for (int cb = 0; cb < 4; ++cb) {
            short8 b8 = __builtin_bit_cast(short8, bf4[ksl][cb]);
            acc[rb][cb] = __builtin_amdgcn_mfma_f32_16x16x32_bf16(a8, b8, acc[rb][cb], 0, 0, 0);
          }
        }
      }
    }
  }

  // epilogue: bias (sum_e c[row][e]*b[e][col]) + store
#pragma unroll
  for (int rb = 0; rb < 4; ++rb) {
    int rloc = wr * 64 + rb * 16 + ((lane >> 4) << 2);
    f32x4 cv[NEXP];
#pragma unroll
    for (int e2 = 0; e2 < NEXP; ++e2)
      cv[e2] = *(const f32x4*)&cT[e2 * 128 + rloc];
#pragma unroll
    for (int cb = 0; cb < 4; ++cb) {
      int cloc = wc * 64 + cb * 16 + (lane & 15);
      f32x4 a = acc[rb][cb];
#pragma unroll
      for (int e2 = 0; e2 < NEXP; ++e2) {
        float bv = bT[e2 * 128 + cloc];
        a[0] += cv[e2][0] * bv;
        a[1] += cv[e2][1] * bv;
        a[2] += cv[e2][2] * bv;
        a[3] += cv[e2][3] * bv;
      }
      float* o = out + (size_t)(trow + rloc) * DIM + (tcol + cloc);
      o[0 * DIM] = a[0];
      o[1 * DIM] = a[1];
      o[2 * DIM] = a[2];
      o[3 * DIM] = a[3];
    }
  }
}

extern "C" void kernel_launch(void* const* d_in, const int* in_sizes, int n_in,
                              void* d_out, int out_size, void* d_ws, size_t ws_size,
                              hipStream_t stream) {
  (void)in_sizes; (void)n_in; (void)out_size; (void)ws_size;
  const float* x   = (const float*)d_in[0];
  const float* srl = (const float*)d_in[1];
  const float* shl = (const float*)d_in[2];
  const float* sW  = (const float*)d_in[3];
  const float* sb  = (const float*)d_in[4];
  const float* hW  = (const float*)d_in[5];
  const float* hb  = (const float*)d_in[6];
  float* out = (float*)d_out;

  // workspace layout (needs ~22.7 MB)
  float*    cws = (float*)d_ws;                     // 16384*10 f32   (655,360 B)
  ushort_t* xb  = (ushort_t*)(cws + TOK * NEXP);    // 16384*512 bf16 (16 MB)
  ushort_t* wt  = xb + (size_t)TOK * DIM;           // 10*512*512 bf16 (5 MB)

  k_router<<<TOK / 256, 256, 0, stream>>>(srl, shl, cws);
  k_cvtx<<<(TOK * DIM) / (8 * 256), 256, 0, stream>>>(x, xb);
  dim3 tb(32, 32, 1), tg(16, 16, 10);
  k_trw<<<tg, tb, 0, stream>>>(sW, hW, wt);
  k_moe<<<512, 256, 0, stream>>>(xb, wt, cws, sb, hb, out);
}